// Round 1
// baseline (274.390 us; speedup 1.0000x reference)
//
#include <hip/hip_runtime.h>
#include <math.h>

#define BATCH 32
#define CIN   128
#define DDIM  64
#define KCB   512
#define HWSZ  4096                       // 64*64
#define NPIX  (BATCH*HWSZ)               // 131072 pixels
#define NOUTQ (8388608)                  // BATCH*DDIM*HWSZ

// ---------------------------------------------------------------------------
// Prep kernel (1 block): transpose conv_w [D][C] -> wT [C][D] so the per-c
// weight column is contiguous (s_load-friendly), precompute ||c_k||^2, and
// zero the loss accumulator slot (harness does not re-poison between replays).
// ---------------------------------------------------------------------------
__global__ __launch_bounds__(256) void vq_prep(
    const float* __restrict__ w,      // [D][C]
    const float* __restrict__ cb,     // [K][D]
    float* __restrict__ wT,           // [C][D]
    float* __restrict__ cbn,          // [K]
    float* __restrict__ loss_slot)
{
    int t = threadIdx.x;
    for (int i = t; i < CIN * DDIM; i += 256) {
        int d = i / CIN;
        int c = i - d * CIN;
        wT[c * DDIM + d] = w[i];
    }
    for (int k = t; k < KCB; k += 256) {
        const float4* row = (const float4*)(cb + k * DDIM);
        float s = 0.f;
        #pragma unroll
        for (int i = 0; i < DDIM / 4; ++i) {
            float4 v = row[i];
            s = fmaf(v.x, v.x, s);
            s = fmaf(v.y, v.y, s);
            s = fmaf(v.z, v.z, s);
            s = fmaf(v.w, v.w, s);
        }
        cbn[k] = s;
    }
    if (t == 0) *loss_slot = 0.f;
}

// ---------------------------------------------------------------------------
// Main fused kernel: one thread per pixel.
//   z[d] = sum_c x[b,c,hw] * w[d,c] + bias[d]        (projection)
//   k*   = argmin_k ||z||^2 - 2 z.c_k + ||c_k||^2    (nearest code)
//   out[b,d,hw] = codebook[k*][d]                     (straight-through fwd)
//   loss += 1.25 * (q - z)^2 / NOUTQ                  (reduced via atomics)
// All w/codebook accesses are wave-uniform -> compiler scalarizes to s_load,
// so the VALU stream is nearly pure v_fmac_f32.
// ---------------------------------------------------------------------------
__global__ __launch_bounds__(256) void vq_main(
    const float* __restrict__ x,      // [B][C][HW]
    const float* __restrict__ bias,   // [D]
    const float* __restrict__ cb,     // [K][D]
    const float* __restrict__ wT,     // [C][D]
    const float* __restrict__ cbn,    // [K]
    float* __restrict__ out,          // [B][D][HW]
    float* __restrict__ loss_slot)
{
    const int p  = blockIdx.x * 256 + threadIdx.x;   // pixel id
    const int b  = p >> 12;                          // / 4096
    const int hw = p & 4095;
    const float* xp = x + ((size_t)b * CIN) * HWSZ + hw;

    // ---- projection ----
    float z[DDIM];
    #pragma unroll
    for (int d = 0; d < DDIM; ++d) z[d] = bias[d];   // uniform -> s_load

    for (int c = 0; c < CIN; ++c) {
        float xv = xp[(size_t)c * HWSZ];             // coalesced vector load
        const float4* wrow = (const float4*)(wT + c * DDIM);  // uniform
        #pragma unroll
        for (int i = 0; i < DDIM / 4; ++i) {
            float4 wv = wrow[i];
            z[4*i+0] = fmaf(xv, wv.x, z[4*i+0]);
            z[4*i+1] = fmaf(xv, wv.y, z[4*i+1]);
            z[4*i+2] = fmaf(xv, wv.z, z[4*i+2]);
            z[4*i+3] = fmaf(xv, wv.w, z[4*i+3]);
        }
    }

    float znorm = 0.f;
    #pragma unroll
    for (int d = 0; d < DDIM; ++d) znorm = fmaf(z[d], z[d], znorm);

    // ---- nearest codebook entry ----
    float best = INFINITY;
    int bestk = 0;
    for (int k = 0; k < KCB; ++k) {
        const float4* crow = (const float4*)(cb + k * DDIM);  // uniform
        float dot = 0.f;
        #pragma unroll
        for (int i = 0; i < DDIM / 4; ++i) {
            float4 cv = crow[i];
            dot = fmaf(z[4*i+0], cv.x, dot);
            dot = fmaf(z[4*i+1], cv.y, dot);
            dot = fmaf(z[4*i+2], cv.z, dot);
            dot = fmaf(z[4*i+3], cv.w, dot);
        }
        float dist = znorm - 2.f * dot + cbn[k];
        if (dist < best) { best = dist; bestk = k; }  // strict < == np.argmin
    }

    // ---- gather, store, loss ----
    const float4* qrow = (const float4*)(cb + bestk * DDIM);  // divergent, L2-hot
    float lsum = 0.f;
    size_t obase = ((size_t)b * DDIM) * HWSZ + hw;
    #pragma unroll
    for (int i = 0; i < DDIM / 4; ++i) {
        float4 qv = qrow[i];
        float d0 = qv.x - z[4*i+0];
        float d1 = qv.y - z[4*i+1];
        float d2 = qv.z - z[4*i+2];
        float d3 = qv.w - z[4*i+3];
        lsum = fmaf(d0, d0, lsum);
        lsum = fmaf(d1, d1, lsum);
        lsum = fmaf(d2, d2, lsum);
        lsum = fmaf(d3, d3, lsum);
        out[obase + (size_t)(4*i+0) * HWSZ] = qv.x;   // coalesced per d-plane
        out[obase + (size_t)(4*i+1) * HWSZ] = qv.y;
        out[obase + (size_t)(4*i+2) * HWSZ] = qv.z;
        out[obase + (size_t)(4*i+3) * HWSZ] = qv.w;
    }

    // wave-level reduce (64 lanes), one atomic per wave
    #pragma unroll
    for (int off = 32; off > 0; off >>= 1)
        lsum += __shfl_down(lsum, off, 64);
    if ((threadIdx.x & 63) == 0)
        atomicAdd(loss_slot, lsum * (1.25f / (float)NOUTQ));
}

extern "C" void kernel_launch(void* const* d_in, const int* in_sizes, int n_in,
                              void* d_out, int out_size, void* d_ws, size_t ws_size,
                              hipStream_t stream) {
    const float* x    = (const float*)d_in[0];   // [32,128,64,64]
    const float* w    = (const float*)d_in[1];   // [64,128]
    const float* bias = (const float*)d_in[2];   // [64]
    const float* cb   = (const float*)d_in[3];   // [512,64]
    float* out = (float*)d_out;                  // 8388608 quantized + 1 loss
    float* wT  = (float*)d_ws;                   // [128][64]
    float* cbn = wT + CIN * DDIM;                // [512]
    float* loss_slot = out + NOUTQ;

    vq_prep<<<1, 256, 0, stream>>>(w, cb, wT, cbn, loss_slot);
    vq_main<<<NPIX / 256, 256, 0, stream>>>(x, bias, cb, wT, cbn, out, loss_slot);
}